// Round 4
// baseline (62.528 us; speedup 1.0000x reference)
//
#include <hip/hip_runtime.h>

#define BTOT 4096
#define G 2               // batch items per block
#define NC 16
#define WIN 247
#define NBLK (BTOT / G)   // 2048 blocks

// ---------------- Kernel 1: conv (tap-parallel streaming) + nonlinearity + projections ----------------
__global__ __launch_bounds__(256, 4) void k_main(
    const float* __restrict__ x,
    const float* __restrict__ Wr, const float* __restrict__ Wi,
    const float* __restrict__ Wnl, const float* __restrict__ Wc,
    const float* __restrict__ Wor, const float* __restrict__ Woi,
    float* __restrict__ out, float* __restrict__ ws)
{
    // W table: k' = k+16, k' in [0,272). WL[k'*16 + c] = {Wr[c][k], Wi[c][k]}, 0 outside [0,247)
    __shared__ float2 WL[272 * 16];     // 34816 B
    __shared__ float WnlS[NC * 60];     // 960 f
    __shared__ float WoS[2 * 160];      // 320 f
    __shared__ float WcS[4];

    const int tid  = threadIdx.x;
    const int lane = tid & 63;
    const int wvid = tid >> 6;          // 0..3
    const int c    = tid & 15;
    const int q    = (tid >> 4) & 3;
    const int ns   = q + 4 * (wvid & 1);     // 0..7
    const int b_loc = wvid >> 1;             // 0..1
    const int b0   = blockIdx.x * G;
    const int n0   = ns * 32;

    // ---- stage W (zero-padded) + small weights ----
    for (int idx = tid; idx < 272 * 16; idx += 256) {
        int kp = idx >> 4, cc = idx & 15;
        int k  = kp - 16;
        float2 v = make_float2(0.f, 0.f);
        if (k >= 0 && k < WIN) { v.x = Wr[cc * WIN + k]; v.y = Wi[cc * WIN + k]; }
        WL[idx] = v;
    }
    for (int idx = tid; idx < NC * 60; idx += 256) WnlS[idx] = Wnl[idx];
    if (tid < 160) { WoS[tid] = Wor[tid]; WoS[160 + tid] = Woi[tid]; }
    if (tid < 4) WcS[tid] = Wc[tid];
    __syncthreads();

    // ---- conv: stream 32 independent float2 x-loads, rolling 10-deep W window ----
    const float2* xp = (const float2*)x + (size_t)(b0 + b_loc) * 4096 + c;  // elem n at xp[n*16]
    const float2* WLc = WL + c;

    float accr[10], acci[10];
    float2 win[10];
    #pragma unroll
    for (int w = 0; w < 10; ++w) { accr[w] = 0.f; acci[w] = 0.f; }

    // preload window W[n0-9 .. n0-1] -> slot (m+10)%10
    #pragma unroll
    for (int m = -9; m < 0; ++m)
        win[m + 10 == 10 ? 0 : m + 10] = WLc[(n0 + m + 16) * 16];

    // x prefetch depth 8, W prefetch depth 2
    float2 xr[8];
    float2 wpre[2];
    #pragma unroll
    for (int j = 0; j < 8; ++j) xr[j] = xp[(n0 + j) * 16];
    wpre[0] = WLc[(n0 + 16) * 16];
    wpre[1] = WLc[(n0 + 17) * 16];

    #pragma unroll
    for (int i = 0; i < 32; ++i) {
        float2 xv = xr[i & 7];
        if (i < 24) xr[i & 7] = xp[(n0 + i + 8) * 16];
        float2 wv = wpre[i & 1];
        if (i < 30) wpre[i & 1] = WLc[(n0 + i + 18) * 16];
        win[i % 10] = wv;
        #pragma unroll
        for (int w = 9; w >= 0; --w) {       // freshest tap (w=0) used last
            float2 ww = win[(i - w + 10) % 10];
            accr[w] = fmaf(xv.x, ww.x, accr[w]);
            acci[w] = fmaf(xv.y, ww.y, acci[w]);
        }
    }

    // ---- reduce over ns: 4 segs within wave via butterfly ----
    #pragma unroll
    for (int w = 0; w < 10; ++w) {
        accr[w] += __shfl_xor(accr[w], 16);
        accr[w] += __shfl_xor(accr[w], 32);
        acci[w] += __shfl_xor(acci[w], 16);
        acci[w] += __shfl_xor(acci[w], 32);
    }

    __syncthreads();                    // all WL conv reads done -> safe to alias
    float* S    = (float*)WL;           // part[2][16][20] : 640 f
    float* fbuf = S + 640;              // [2][16][20]     : 640 f
    float* crS  = S + 1280;             // 320 f
    float* ciS  = S + 1600;             // 320 f
    float* red  = S + 1920;             // 32 f
    float* redq = S + 1952;             // 32 f

    if ((wvid & 1) == 0 && lane < 16) { // waves 0,2 write their 4-seg sums
        #pragma unroll
        for (int w = 0; w < 10; ++w) {
            S[b_loc * 320 + lane * 20 + w]      = accr[w];
            S[b_loc * 320 + lane * 20 + 10 + w] = acci[w];
        }
    }
    __syncthreads();
    if ((wvid & 1) == 1 && lane < 16) { // waves 1,3 finalize + amp nonlinearity
        #pragma unroll
        for (int w = 0; w < 10; ++w) {
            float fr = S[b_loc * 320 + lane * 20 + w]      + accr[w];
            float fi = S[b_loc * 320 + lane * 20 + 10 + w] + acci[w];
            float amp = fr * fr + fi * fi;
            fbuf[b_loc * 320 + lane * 20 + w]      = amp * fr;
            fbuf[b_loc * 320 + lane * 20 + 10 + w] = amp * fi;
        }
    }
    __syncthreads();

    // ---- phase 3: neighbor einsum + coeff + output-window weights ----
    for (int idx = tid; idx < G * 160; idx += 256) {
        int bb = idx / 160; int r = idx - bb * 160;
        int cc = r / 10;    int w = r - cc * 10;
        const float* f3 = fbuf + bb * 320;
        const float* wn = WnlS + cc * 60;
        float s0 = 0.f, s1 = 0.f;
        #pragma unroll
        for (int j = 0; j < NC; ++j) {
            if (j != cc) {
                int jj = (j > cc) ? (j - 1) : j;
                float f3r = f3[j * 20 + w];
                float f3i = f3[j * 20 + 10 + w];
                s0 += f3r * wn[jj]      + f3i * wn[15 + jj];
                s1 += f3r * wn[30 + jj] + f3i * wn[45 + jj];
            }
        }
        float p0 = s0 * WcS[0] + s1 * WcS[1];
        float p1 = s0 * WcS[2] + s1 * WcS[3];
        crS[idx] = p0 * WoS[cc * 10 + w];
        ciS[idx] = p1 * WoS[160 + cc * 10 + w];
    }
    __syncthreads();

    // ---- phase 4: sum over w, write out + BN partials ----
    if (tid < G * NC) {
        int bb = tid >> 4; int cc = tid & 15;
        float orr = 0.f, oii = 0.f;
        #pragma unroll
        for (int w = 0; w < 10; ++w) {
            orr += crS[bb * 160 + cc * 10 + w];
            oii += ciS[bb * 160 + cc * 10 + w];
        }
        size_t o = ((size_t)(b0 + bb) * NC + cc) * 2;
        out[o]     = orr;
        out[o + 1] = oii;
        red[tid]  = orr + oii;
        redq[tid] = orr * orr + oii * oii;
    }
    __syncthreads();
    if (tid < NC) {
        float s = 0.f, qq = 0.f;
        #pragma unroll
        for (int bb = 0; bb < G; ++bb) { s += red[bb * 16 + tid]; qq += redq[bb * 16 + tid]; }
        ws[(tid * NBLK + blockIdx.x) * 2]     = s;
        ws[(tid * NBLK + blockIdx.x) * 2 + 1] = qq;
    }
}

// ---------------- Kernel 2: reduce partials -> per-channel scale/shift ----------------
__global__ __launch_bounds__(256) void k_bnstat(
    const float* __restrict__ ws_in, float* __restrict__ ws_ab,
    const float* __restrict__ gamma, const float* __restrict__ beta)
{
    const int cch = blockIdx.x;
    const int tid = threadIdx.x;
    float s = 0.f, q = 0.f;
    for (int i = tid; i < NBLK; i += 256) {
        s += ws_in[(cch * NBLK + i) * 2];
        q += ws_in[(cch * NBLK + i) * 2 + 1];
    }
    #pragma unroll
    for (int off = 32; off; off >>= 1) {
        s += __shfl_down(s, off, 64);
        q += __shfl_down(q, off, 64);
    }
    __shared__ float rs[4], rq[4];
    const int wv = tid >> 6;
    if ((tid & 63) == 0) { rs[wv] = s; rq[wv] = q; }
    __syncthreads();
    if (tid == 0) {
        s = rs[0] + rs[1] + rs[2] + rs[3];
        q = rq[0] + rq[1] + rq[2] + rq[3];
        const float inv_n = 1.f / (BTOT * 2.f);
        float mu  = s * inv_n;
        float var = q * inv_n - mu * mu;
        float sc  = gamma[cch] * rsqrtf(var + 1e-5f);
        ws_ab[cch]      = sc;
        ws_ab[16 + cch] = beta[cch] - mu * sc;
    }
}

// ---------------- Kernel 3: apply BN affine in place ----------------
__global__ __launch_bounds__(256) void k_bnapply(
    float* __restrict__ out, const float* __restrict__ ws_ab)
{
    __shared__ float A[16], Bb[16];
    const int tid = threadIdx.x;
    if (tid < 16) { A[tid] = ws_ab[tid]; Bb[tid] = ws_ab[16 + tid]; }
    __syncthreads();
    int idx = blockIdx.x * 256 + tid;
    if (idx < BTOT * NC * 2) {
        int cch = (idx >> 1) & 15;
        out[idx] = out[idx] * A[cch] + Bb[cch];
    }
}

extern "C" void kernel_launch(void* const* d_in, const int* in_sizes, int n_in,
                              void* d_out, int out_size, void* d_ws, size_t ws_size,
                              hipStream_t stream)
{
    const float* x    = (const float*)d_in[0];
    const float* Wr   = (const float*)d_in[1];
    const float* Wi   = (const float*)d_in[2];
    const float* Wnl  = (const float*)d_in[3];
    const float* Wc   = (const float*)d_in[4];
    const float* Wor  = (const float*)d_in[5];
    const float* Woi  = (const float*)d_in[6];
    const float* gam  = (const float*)d_in[7];
    const float* bet  = (const float*)d_in[8];
    float* out = (float*)d_out;
    float* ws  = (float*)d_ws;
    float* ws_ab = ws + NC * NBLK * 2;   // 65536 floats of partials, then 32 floats scale/shift

    k_main<<<NBLK, 256, 0, stream>>>(x, Wr, Wi, Wnl, Wc, Wor, Woi, out, ws);
    k_bnstat<<<NC, 256, 0, stream>>>(ws, ws_ab, gam, bet);
    k_bnapply<<<(BTOT * NC * 2 + 255) / 256, 256, 0, stream>>>(out, ws_ab);
}

// Round 5
// 53.772 us; speedup vs baseline: 1.1628x; 1.1628x over previous
//
#include <hip/hip_runtime.h>

#define BTOT 4096
#define G 4               // batch items per block (one per wave)
#define NC 16
#define WIN 247
#define NBLK (BTOT / G)   // 1024 blocks

// ---------------- Kernel 1: conv (float4 streaming) + nonlinearity + projections ----------------
__global__ __launch_bounds__(256, 2) void k_main(
    const float* __restrict__ x,
    const float* __restrict__ Wr, const float* __restrict__ Wi,
    const float* __restrict__ Wnl, const float* __restrict__ Wc,
    const float* __restrict__ Wor, const float* __restrict__ Woi,
    float* __restrict__ out, float* __restrict__ ws)
{
    // WL4[(k+9)*8 + cp] = {Wr[2cp][k], Wi[2cp][k], Wr[2cp+1][k], Wi[2cp+1][k]}, 0 outside [0,247)
    __shared__ float4 WL4[265 * 8];     // 33920 B
    __shared__ float WnlS[NC * 60];     // 960 f
    __shared__ float WoS[2 * 160];      // 320 f
    __shared__ float WcS[4];

    const int tid   = threadIdx.x;
    const int lane  = tid & 63;
    const int b_loc = tid >> 6;         // wave = one batch item
    const int cp    = lane & 7;         // channel pair: c0=2cp, c1=2cp+1
    const int ns    = lane >> 3;        // n-segment 0..7
    const int n0    = ns * 32;
    const int b0    = blockIdx.x * G;

    // ---- stage W table (zero-padded) + small weights ----
    for (int idx = tid; idx < 265 * 8; idx += 256) {
        int m = idx >> 3, cc = idx & 7;
        int k = m - 9;
        float4 v = make_float4(0.f, 0.f, 0.f, 0.f);
        if (k >= 0 && k < WIN) {
            v.x = Wr[(2 * cc) * WIN + k];
            v.y = Wi[(2 * cc) * WIN + k];
            v.z = Wr[(2 * cc + 1) * WIN + k];
            v.w = Wi[(2 * cc + 1) * WIN + k];
        }
        WL4[idx] = v;
    }
    for (int idx = tid; idx < NC * 60; idx += 256) WnlS[idx] = Wnl[idx];
    if (tid < 160) { WoS[tid] = Wor[tid]; WoS[160 + tid] = Woi[tid]; }
    if (tid < 4) WcS[tid] = Wc[tid];
    __syncthreads();

    // x[b, n, c, ri] as float4: element (b, n, cp) at xp[n*8], spans channels 2cp, 2cp+1
    const float4* xp = (const float4*)x + (size_t)(b0 + b_loc) * 2048 + cp;
    // W window source: Wb[t*8] = tap k = n0 + t - 9  (t in [0,41))
    const float4* Wb = WL4 + n0 * 8 + cp;

    float ar0[10], ai0[10], ar1[10], ai1[10];
    float4 win[10], xr[4], wpre;
    #pragma unroll
    for (int w = 0; w < 10; ++w) { ar0[w] = 0.f; ai0[w] = 0.f; ar1[w] = 0.f; ai1[w] = 0.f; }

    #pragma unroll
    for (int t = 0; t < 10; ++t) win[t] = Wb[t * 8];
    wpre = Wb[10 * 8];
    #pragma unroll
    for (int j = 0; j < 4; ++j) xr[j] = xp[(n0 + j) * 8];

    // ---- conv: 32 n-steps; x prefetch depth 4; W prefetch depth 2 (wpre -> win) ----
    #pragma unroll
    for (int i = 0; i < 32; ++i) {
        float4 xv = xr[i & 3];
        if (i < 28) xr[i & 3] = xp[(n0 + i + 4) * 8];
        #pragma unroll
        for (int w = 0; w < 10; ++w) {
            float4 t4 = win[(i + 9 - w) % 10];      // tap k = n0 + i - w
            ar0[w] = fmaf(xv.x, t4.x, ar0[w]);
            ai0[w] = fmaf(xv.y, t4.y, ai0[w]);
            ar1[w] = fmaf(xv.z, t4.z, ar1[w]);
            ai1[w] = fmaf(xv.w, t4.w, ai1[w]);
        }
        win[i % 10] = wpre;                          // becomes tap t = i+10
        if (i < 30) wpre = Wb[(i + 11) * 8];
    }

    // ---- reduce over ns (lane bits 3,4,5) ----
    #pragma unroll
    for (int w = 0; w < 10; ++w) {
        ar0[w] += __shfl_xor(ar0[w], 8);  ar0[w] += __shfl_xor(ar0[w], 16);  ar0[w] += __shfl_xor(ar0[w], 32);
        ai0[w] += __shfl_xor(ai0[w], 8);  ai0[w] += __shfl_xor(ai0[w], 16);  ai0[w] += __shfl_xor(ai0[w], 32);
        ar1[w] += __shfl_xor(ar1[w], 8);  ar1[w] += __shfl_xor(ar1[w], 16);  ar1[w] += __shfl_xor(ar1[w], 32);
        ai1[w] += __shfl_xor(ai1[w], 8);  ai1[w] += __shfl_xor(ai1[w], 16);  ai1[w] += __shfl_xor(ai1[w], 32);
    }

    __syncthreads();                    // conv reads of WL4 done -> safe to alias
    float* S    = (float*)WL4;
    float* fbuf = S;                    // [b][c][{r,i}][w] : G*320 = 1280 f
    float* crS  = S + 1280;             // 640 f
    float* ciS  = S + 1920;             // 640 f
    float* red  = S + 2560;             // 64 f
    float* redq = S + 2624;             // 64 f

    // ---- amp nonlinearity (values fully reduced in-register) ----
    if (lane < 8) {
        #pragma unroll
        for (int w = 0; w < 10; ++w) {
            float fr0 = ar0[w], fi0 = ai0[w];
            float a0  = fr0 * fr0 + fi0 * fi0;
            fbuf[b_loc * 320 + (2 * cp) * 20 + w]      = a0 * fr0;
            fbuf[b_loc * 320 + (2 * cp) * 20 + 10 + w] = a0 * fi0;
            float fr1 = ar1[w], fi1 = ai1[w];
            float a1  = fr1 * fr1 + fi1 * fi1;
            fbuf[b_loc * 320 + (2 * cp + 1) * 20 + w]      = a1 * fr1;
            fbuf[b_loc * 320 + (2 * cp + 1) * 20 + 10 + w] = a1 * fi1;
        }
    }
    __syncthreads();

    // ---- phase 3: neighbor einsum + coeff + output-window weights ----
    for (int idx = tid; idx < G * 160; idx += 256) {
        int bb = idx / 160; int r = idx - bb * 160;
        int cc = r / 10;    int w = r - cc * 10;
        const float* f3 = fbuf + bb * 320;
        const float* wn = WnlS + cc * 60;
        float s0 = 0.f, s1 = 0.f;
        #pragma unroll
        for (int j = 0; j < NC; ++j) {
            if (j != cc) {
                int jj = (j > cc) ? (j - 1) : j;
                float f3r = f3[j * 20 + w];
                float f3i = f3[j * 20 + 10 + w];
                s0 += f3r * wn[jj]      + f3i * wn[15 + jj];
                s1 += f3r * wn[30 + jj] + f3i * wn[45 + jj];
            }
        }
        float p0 = s0 * WcS[0] + s1 * WcS[1];
        float p1 = s0 * WcS[2] + s1 * WcS[3];
        crS[idx] = p0 * WoS[cc * 10 + w];
        ciS[idx] = p1 * WoS[160 + cc * 10 + w];
    }
    __syncthreads();

    // ---- phase 4: sum over w, write out + BN partials ----
    if (tid < G * NC) {
        int bb = tid >> 4; int cc = tid & 15;
        float orr = 0.f, oii = 0.f;
        #pragma unroll
        for (int w = 0; w < 10; ++w) {
            orr += crS[bb * 160 + cc * 10 + w];
            oii += ciS[bb * 160 + cc * 10 + w];
        }
        size_t o = ((size_t)(b0 + bb) * NC + cc) * 2;
        out[o]     = orr;
        out[o + 1] = oii;
        red[tid]  = orr + oii;
        redq[tid] = orr * orr + oii * oii;
    }
    __syncthreads();
    if (tid < NC) {
        float s = 0.f, qq = 0.f;
        #pragma unroll
        for (int bb = 0; bb < G; ++bb) { s += red[bb * 16 + tid]; qq += redq[bb * 16 + tid]; }
        ws[(tid * NBLK + blockIdx.x) * 2]     = s;
        ws[(tid * NBLK + blockIdx.x) * 2 + 1] = qq;
    }
}

// ---------------- Kernel 2: reduce partials -> per-channel scale/shift ----------------
__global__ __launch_bounds__(256) void k_bnstat(
    const float* __restrict__ ws_in, float* __restrict__ ws_ab,
    const float* __restrict__ gamma, const float* __restrict__ beta)
{
    const int cch = blockIdx.x;
    const int tid = threadIdx.x;
    float s = 0.f, q = 0.f;
    for (int i = tid; i < NBLK; i += 256) {
        s += ws_in[(cch * NBLK + i) * 2];
        q += ws_in[(cch * NBLK + i) * 2 + 1];
    }
    #pragma unroll
    for (int off = 32; off; off >>= 1) {
        s += __shfl_down(s, off, 64);
        q += __shfl_down(q, off, 64);
    }
    __shared__ float rs[4], rq[4];
    const int wv = tid >> 6;
    if ((tid & 63) == 0) { rs[wv] = s; rq[wv] = q; }
    __syncthreads();
    if (tid == 0) {
        s = rs[0] + rs[1] + rs[2] + rs[3];
        q = rq[0] + rq[1] + rq[2] + rq[3];
        const float inv_n = 1.f / (BTOT * 2.f);
        float mu  = s * inv_n;
        float var = q * inv_n - mu * mu;
        float sc  = gamma[cch] * rsqrtf(var + 1e-5f);
        ws_ab[cch]      = sc;
        ws_ab[16 + cch] = beta[cch] - mu * sc;
    }
}

// ---------------- Kernel 3: apply BN affine in place ----------------
__global__ __launch_bounds__(256) void k_bnapply(
    float* __restrict__ out, const float* __restrict__ ws_ab)
{
    __shared__ float A[16], Bb[16];
    const int tid = threadIdx.x;
    if (tid < 16) { A[tid] = ws_ab[tid]; Bb[tid] = ws_ab[16 + tid]; }
    __syncthreads();
    int idx = blockIdx.x * 256 + tid;
    if (idx < BTOT * NC * 2) {
        int cch = (idx >> 1) & 15;
        out[idx] = out[idx] * A[cch] + Bb[cch];
    }
}

extern "C" void kernel_launch(void* const* d_in, const int* in_sizes, int n_in,
                              void* d_out, int out_size, void* d_ws, size_t ws_size,
                              hipStream_t stream)
{
    const float* x    = (const float*)d_in[0];
    const float* Wr   = (const float*)d_in[1];
    const float* Wi   = (const float*)d_in[2];
    const float* Wnl  = (const float*)d_in[3];
    const float* Wc   = (const float*)d_in[4];
    const float* Wor  = (const float*)d_in[5];
    const float* Woi  = (const float*)d_in[6];
    const float* gam  = (const float*)d_in[7];
    const float* bet  = (const float*)d_in[8];
    float* out = (float*)d_out;
    float* ws  = (float*)d_ws;
    float* ws_ab = ws + NC * NBLK * 2;   // 32768 floats of partials, then 32 floats scale/shift

    k_main<<<NBLK, 256, 0, stream>>>(x, Wr, Wi, Wnl, Wc, Wor, Woi, out, ws);
    k_bnstat<<<NC, 256, 0, stream>>>(ws, ws_ab, gam, bet);
    k_bnapply<<<(BTOT * NC * 2 + 255) / 256, 256, 0, stream>>>(out, ws_ab);
}